// Round 1
// baseline (473.087 us; speedup 1.0000x reference)
//
#include <hip/hip_runtime.h>
#include <hip/hip_bf16.h>

#define N_NODES 50000
#define N_EDGES 1600000
#define D 512

typedef __attribute__((ext_vector_type(8))) short short8;
typedef __attribute__((ext_vector_type(4))) float f32x4;
typedef __attribute__((ext_vector_type(2))) float f32x2;
typedef __attribute__((ext_vector_type(8))) unsigned short u16x8;

__device__ __forceinline__ void async_copy16(const void* g, void* l) {
    __builtin_amdgcn_global_load_lds(
        (const __attribute__((address_space(1))) unsigned int*)g,
        (__attribute__((address_space(3))) unsigned int*)l, 16, 0, 0);
}

// --- X fp32 -> bf16 prepass (Xb lives in d_out's first 51.2 MB, overwritten later) ---
__global__ __launch_bounds__(256) void cvt_kernel(const float* __restrict__ X,
                                                  unsigned short* __restrict__ Xb) {
    size_t idx = (size_t)(blockIdx.x * 256 + threadIdx.x) * 8;
    f32x4 v0 = *(const f32x4*)(X + idx);
    f32x4 v1 = *(const f32x4*)(X + idx + 4);
    u16x8 u;
#pragma unroll
    for (int k = 0; k < 4; ++k) {
        u[k]     = __bfloat16_as_ushort(__float2bfloat16(v0[k]));
        u[k + 4] = __bfloat16_as_ushort(__float2bfloat16(v1[k]));
    }
    *(u16x8*)(Xb + idx) = u;
}

// --- W transpose + cast: Wt[n][k] = bf16(W[k][n]) ---
__global__ __launch_bounds__(256) void wt_kernel(const float* __restrict__ W,
                                                 unsigned short* __restrict__ Wt) {
    int idx = blockIdx.x * 256 + threadIdx.x;
    int k = idx >> 9;
    int n = idx & 511;
    Wt[n * D + k] = __bfloat16_as_ushort(__float2bfloat16(W[k * D + n]));
}

// --- CSR row_start from sorted adj_rows ---
__global__ __launch_bounds__(256) void rowptr_kernel(const int* __restrict__ rows,
                                                     int* __restrict__ row_start) {
    int r = blockIdx.x * 256 + threadIdx.x;
    if (r > N_NODES) return;
    int lo = 0, hi = N_EDGES;
    while (lo < hi) {
        int mid = (lo + hi) >> 1;
        if (rows[mid] < r) lo = mid + 1; else hi = mid;
    }
    row_start[r] = lo;
}

// --- support = bf16(Xb @ Wt^T) — UNCHANGED (attribution control) ---
__global__ __launch_bounds__(256) void gemm_kernel(const unsigned short* __restrict__ Xb,
                                                   const unsigned short* __restrict__ Wt,
                                                   __hip_bfloat16* __restrict__ support) {
    __shared__ unsigned short As[128 * 32];
    __shared__ unsigned short Bs[128 * 32];

    const int t = threadIdx.x;
    const int lane = t & 63;
    const int wave = t >> 6;
    const int wm = (wave & 1) * 64;
    const int wn = (wave >> 1) * 64;
    const int m0 = blockIdx.x * 128;
    const int n0 = blockIdx.y * 128;
    const int l15 = lane & 15;
    const int quad = lane >> 4;

    f32x4 acc[4][4];
#pragma unroll
    for (int i = 0; i < 4; ++i)
#pragma unroll
        for (int j = 0; j < 4; ++j) acc[i][j] = (f32x4)(0.0f);

    const int srow = t >> 2;
    const int skb = (t & 3) * 8;
    int gra = m0 + srow;        if (gra > N_NODES - 1) gra = N_NODES - 1;
    int grb = m0 + 64 + srow;   if (grb > N_NODES - 1) grb = N_NODES - 1;
    const size_t aoff0 = (size_t)gra * D + skb;
    const size_t aoff1 = (size_t)grb * D + skb;
    const size_t boff0 = (size_t)(n0 + srow) * D + skb;
    const size_t boff1 = (size_t)(n0 + 64 + srow) * D + skb;
    unsigned short* lA = As + t * 8;
    unsigned short* lB = Bs + t * 8;

    for (int kt = 0; kt < D / 32; ++kt) {
        const int k0 = kt * 32;
        async_copy16(Xb + aoff0 + k0, lA);
        async_copy16(Xb + aoff1 + k0, lA + 2048);
        async_copy16(Wt + boff0 + k0, lB);
        async_copy16(Wt + boff1 + k0, lB + 2048);
        __syncthreads();

        short8 af[4], bf[4];
#pragma unroll
        for (int i = 0; i < 4; ++i) af[i] = *(const short8*)(As + (wm + i * 16 + l15) * 32 + quad * 8);
#pragma unroll
        for (int j = 0; j < 4; ++j) bf[j] = *(const short8*)(Bs + (wn + j * 16 + l15) * 32 + quad * 8);
#pragma unroll
        for (int i = 0; i < 4; ++i)
#pragma unroll
            for (int j = 0; j < 4; ++j)
                acc[i][j] = __builtin_amdgcn_mfma_f32_16x16x32_bf16(af[i], bf[j], acc[i][j], 0, 0, 0);
        __syncthreads();
    }

#pragma unroll
    for (int i = 0; i < 4; ++i) {
        int grow = m0 + wm + i * 16 + quad * 4;
#pragma unroll
        for (int j = 0; j < 4; ++j) {
            int gc = n0 + wn + j * 16 + l15;
#pragma unroll
            for (int rr = 0; rr < 4; ++rr) {
                int gr = grow + rr;
                if (gr < N_NODES)
                    support[(size_t)gr * D + gc] = __float2bfloat16(acc[i][j][rr]);
            }
        }
    }
}

// --- SpMM v2: wave-per-row, 16B gathers (dwordx4 = 8 bf16/lane), 4-edge unroll ---
// Each block = 4 waves = 4 rows. Lane owns cols [8*lane, 8*lane+8); 64 lanes x 16B
// = full 1KB support row per edge, perfectly coalesced. Accumulation order per
// column identical to v1 (sequential over CSR edges) -> bit-identical numerics.
__device__ __forceinline__ void fma8(float* acc, uint4 h, float v) {
#pragma unroll
    for (int d = 0; d < 4; ++d) {
        unsigned int w = (&h.x)[d];
        acc[2 * d]     += v * __uint_as_float(w << 16);          // lo bf16
        acc[2 * d + 1] += v * __uint_as_float(w & 0xffff0000u);  // hi bf16
    }
}

__global__ __launch_bounds__(256) void spmm_kernel(const unsigned short* __restrict__ support,
                                                   const int* __restrict__ cols,
                                                   const float* __restrict__ vals,
                                                   const int* __restrict__ row_start,
                                                   float* __restrict__ out) {
    const int t = threadIdx.x;
    const int lane = t & 63;
    const int wave = t >> 6;
    const int r = blockIdx.x * 4 + wave;     // grid = 12500 * 4 = 50000 exact
    const int s = row_start[r];
    const int e = row_start[r + 1];
    const int co = lane * 8;                 // 8 bf16 columns per lane

    float acc[8];
#pragma unroll
    for (int k = 0; k < 8; ++k) acc[k] = 0.f;

    int i = s;
    for (; i + 4 <= e; i += 4) {
        int c[4]; float v[4]; uint4 h[4];
#pragma unroll
        for (int k = 0; k < 4; ++k) { c[k] = cols[i + k]; v[k] = vals[i + k]; }
#pragma unroll
        for (int k = 0; k < 4; ++k)
            h[k] = *(const uint4*)(support + (size_t)c[k] * D + co);
#pragma unroll
        for (int k = 0; k < 4; ++k) fma8(acc, h[k], v[k]);
    }
    for (; i < e; ++i) {
        uint4 h = *(const uint4*)(support + (size_t)cols[i] * D + co);
        fma8(acc, h, vals[i]);
    }

    f32x4 o0, o1;
#pragma unroll
    for (int k = 0; k < 4; ++k) { o0[k] = acc[k]; o1[k] = acc[k + 4]; }
    float* op = out + (size_t)r * D + co;
    // nontemporal: out is streamed once; keep it out of L2 so gathers keep their lines
    __builtin_nontemporal_store(o0, (f32x4*)op);
    __builtin_nontemporal_store(o1, (f32x4*)(op + 4));
}

extern "C" void kernel_launch(void* const* d_in, const int* in_sizes, int n_in,
                              void* d_out, int out_size, void* d_ws, size_t ws_size,
                              hipStream_t stream) {
    (void)in_sizes; (void)n_in; (void)out_size; (void)ws_size;
    const float* X    = (const float*)d_in[0];
    const float* W    = (const float*)d_in[1];
    const int* rows   = (const int*)d_in[2];
    const int* cols   = (const int*)d_in[3];
    const float* vals = (const float*)d_in[4];
    float* out = (float*)d_out;

    unsigned short* support = (unsigned short*)d_ws;            // 51.2 MB
    unsigned short* Wt      = support + (size_t)N_NODES * D;    // 0.5 MB
    int* row_start          = (int*)(Wt + (size_t)D * D);       // 200 KB
    unsigned short* Xb = (unsigned short*)d_out;                // scratch in d_out, overwritten by spmm

    cvt_kernel<<<12500, 256, 0, stream>>>(X, Xb);
    wt_kernel<<<(D * D) / 256, 256, 0, stream>>>(W, Wt);
    rowptr_kernel<<<(N_NODES + 256) / 256, 256, 0, stream>>>(rows, row_start);

    dim3 gg((N_NODES + 127) / 128, D / 128);
    gemm_kernel<<<gg, 256, 0, stream>>>(Xb, Wt, (__hip_bfloat16*)support);

    spmm_kernel<<<12500, 256, 0, stream>>>(support, cols, vals, row_start, out);
}

// Round 2
// 470.283 us; speedup vs baseline: 1.0060x; 1.0060x over previous
//
#include <hip/hip_runtime.h>
#include <hip/hip_bf16.h>

#define N_NODES 50000
#define N_EDGES 1600000
#define D 512

typedef __attribute__((ext_vector_type(8))) short short8;
typedef __attribute__((ext_vector_type(4))) float f32x4;
typedef __attribute__((ext_vector_type(2))) float f32x2;
typedef __attribute__((ext_vector_type(8))) unsigned short u16x8;

__device__ __forceinline__ void async_copy16(const void* g, void* l) {
    __builtin_amdgcn_global_load_lds(
        (const __attribute__((address_space(1))) unsigned int*)g,
        (__attribute__((address_space(3))) unsigned int*)l, 16, 0, 0);
}

// --- X fp32 -> bf16 prepass (Xb lives in d_out's first 51.2 MB, overwritten later) ---
__global__ __launch_bounds__(256) void cvt_kernel(const float* __restrict__ X,
                                                  unsigned short* __restrict__ Xb) {
    size_t idx = (size_t)(blockIdx.x * 256 + threadIdx.x) * 8;
    f32x4 v0 = *(const f32x4*)(X + idx);
    f32x4 v1 = *(const f32x4*)(X + idx + 4);
    u16x8 u;
#pragma unroll
    for (int k = 0; k < 4; ++k) {
        u[k]     = __bfloat16_as_ushort(__float2bfloat16(v0[k]));
        u[k + 4] = __bfloat16_as_ushort(__float2bfloat16(v1[k]));
    }
    *(u16x8*)(Xb + idx) = u;
}

// --- W transpose + cast: Wt[n][k] = bf16(W[k][n]) ---
__global__ __launch_bounds__(256) void wt_kernel(const float* __restrict__ W,
                                                 unsigned short* __restrict__ Wt) {
    int idx = blockIdx.x * 256 + threadIdx.x;
    int k = idx >> 9;
    int n = idx & 511;
    Wt[n * D + k] = __bfloat16_as_ushort(__float2bfloat16(W[k * D + n]));
}

// --- CSR row_start from sorted adj_rows ---
__global__ __launch_bounds__(256) void rowptr_kernel(const int* __restrict__ rows,
                                                     int* __restrict__ row_start) {
    int r = blockIdx.x * 256 + threadIdx.x;
    if (r > N_NODES) return;
    int lo = 0, hi = N_EDGES;
    while (lo < hi) {
        int mid = (lo + hi) >> 1;
        if (rows[mid] < r) lo = mid + 1; else hi = mid;
    }
    row_start[r] = lo;
}

// --- support = bf16(Xb @ Wt^T) ---
// v3: 2-phase double-buffered pipeline (T3 minimum recipe): issue STAGE(next K-tile)
// BEFORE computing current tile; ONE barrier per K-iter (was 2). global_load_lds
// latency hides under ds_read+MFMA instead of being exposed on the critical path
// of every one of the 16 short K-iterations. Fragment layout/epilogue unchanged.
__global__ __launch_bounds__(256) void gemm_kernel(const unsigned short* __restrict__ Xb,
                                                   const unsigned short* __restrict__ Wt,
                                                   __hip_bfloat16* __restrict__ support) {
    __shared__ unsigned short As[2][128 * 32];
    __shared__ unsigned short Bs[2][128 * 32];

    const int t = threadIdx.x;
    const int lane = t & 63;
    const int wave = t >> 6;
    const int wm = (wave & 1) * 64;
    const int wn = (wave >> 1) * 64;
    const int m0 = blockIdx.x * 128;
    const int n0 = blockIdx.y * 128;
    const int l15 = lane & 15;
    const int quad = lane >> 4;

    f32x4 acc[4][4];
#pragma unroll
    for (int i = 0; i < 4; ++i)
#pragma unroll
        for (int j = 0; j < 4; ++j) acc[i][j] = (f32x4)(0.0f);

    const int srow = t >> 2;
    const int skb = (t & 3) * 8;
    int gra = m0 + srow;        if (gra > N_NODES - 1) gra = N_NODES - 1;
    int grb = m0 + 64 + srow;   if (grb > N_NODES - 1) grb = N_NODES - 1;
    const size_t aoff0 = (size_t)gra * D + skb;
    const size_t aoff1 = (size_t)grb * D + skb;
    const size_t boff0 = (size_t)(n0 + srow) * D + skb;
    const size_t boff1 = (size_t)(n0 + 64 + srow) * D + skb;
    const int lofs = t * 8;

    // prologue: stage K-tile 0 into buffer 0
    async_copy16(Xb + aoff0, As[0] + lofs);
    async_copy16(Xb + aoff1, As[0] + lofs + 2048);
    async_copy16(Wt + boff0, Bs[0] + lofs);
    async_copy16(Wt + boff1, Bs[0] + lofs + 2048);
    __syncthreads();   // drains vmcnt(0): buffer 0 ready

    int cur = 0;
    for (int kt = 0; kt < D / 32; ++kt) {
        // issue next tile's loads first — in flight during this tile's compute
        if (kt < D / 32 - 1) {
            const int k0 = (kt + 1) * 32;
            async_copy16(Xb + aoff0 + k0, As[cur ^ 1] + lofs);
            async_copy16(Xb + aoff1 + k0, As[cur ^ 1] + lofs + 2048);
            async_copy16(Wt + boff0 + k0, Bs[cur ^ 1] + lofs);
            async_copy16(Wt + boff1 + k0, Bs[cur ^ 1] + lofs + 2048);
        }

        short8 af[4], bf[4];
#pragma unroll
        for (int i = 0; i < 4; ++i) af[i] = *(const short8*)(As[cur] + (wm + i * 16 + l15) * 32 + quad * 8);
#pragma unroll
        for (int j = 0; j < 4; ++j) bf[j] = *(const short8*)(Bs[cur] + (wn + j * 16 + l15) * 32 + quad * 8);
#pragma unroll
        for (int i = 0; i < 4; ++i)
#pragma unroll
            for (int j = 0; j < 4; ++j)
                acc[i][j] = __builtin_amdgcn_mfma_f32_16x16x32_bf16(af[i], bf[j], acc[i][j], 0, 0, 0);

        __syncthreads();   // one barrier/iter: drains this iter's stage + all ds_reads
        cur ^= 1;
    }

#pragma unroll
    for (int i = 0; i < 4; ++i) {
        int grow = m0 + wm + i * 16 + quad * 4;
#pragma unroll
        for (int j = 0; j < 4; ++j) {
            int gc = n0 + wn + j * 16 + l15;
#pragma unroll
            for (int rr = 0; rr < 4; ++rr) {
                int gr = grow + rr;
                if (gr < N_NODES)
                    support[(size_t)gr * D + gc] = __float2bfloat16(acc[i][j][rr]);
            }
        }
    }
}

// --- SpMM: block per row (r0 proven layout), 8-edge unroll, nt-stores ---
// (reverted from wave-per-row v2: identical FETCH, worse occupancy/latency hiding)
__global__ __launch_bounds__(256) void spmm_kernel(const unsigned short* __restrict__ support,
                                                   const int* __restrict__ cols,
                                                   const float* __restrict__ vals,
                                                   const int* __restrict__ row_start,
                                                   float* __restrict__ out) {
    const int r = blockIdx.x;
    const int t = threadIdx.x;           // thread owns cols 2t, 2t+1
    const int s = row_start[r];
    const int e = row_start[r + 1];
    const size_t co = 2 * t;

    float ax = 0.f, ay = 0.f;
    int i = s;
    for (; i + 8 <= e; i += 8) {
        int c[8]; float v[8]; unsigned int h[8];
#pragma unroll
        for (int k = 0; k < 8; ++k) { c[k] = cols[i + k]; v[k] = vals[i + k]; }
#pragma unroll
        for (int k = 0; k < 8; ++k)
            h[k] = *(const unsigned int*)(support + (size_t)c[k] * D + co);
#pragma unroll
        for (int k = 0; k < 8; ++k) {
            ax += v[k] * __uint_as_float(h[k] << 16);          // lo bf16
            ay += v[k] * __uint_as_float(h[k] & 0xffff0000u);  // hi bf16
        }
    }
    for (; i < e; ++i) {
        int c = cols[i];
        float v = vals[i];
        unsigned int h = *(const unsigned int*)(support + (size_t)c * D + co);
        ax += v * __uint_as_float(h << 16);
        ay += v * __uint_as_float(h & 0xffff0000u);
    }
    f32x2 o; o[0] = ax; o[1] = ay;
    // nontemporal: out is streamed once; keep it out of L2 so gathers keep their lines
    __builtin_nontemporal_store(o, (f32x2*)(out + (size_t)r * D + co));
}

extern "C" void kernel_launch(void* const* d_in, const int* in_sizes, int n_in,
                              void* d_out, int out_size, void* d_ws, size_t ws_size,
                              hipStream_t stream) {
    (void)in_sizes; (void)n_in; (void)out_size; (void)ws_size;
    const float* X    = (const float*)d_in[0];
    const float* W    = (const float*)d_in[1];
    const int* rows   = (const int*)d_in[2];
    const int* cols   = (const int*)d_in[3];
    const float* vals = (const float*)d_in[4];
    float* out = (float*)d_out;

    unsigned short* support = (unsigned short*)d_ws;            // 51.2 MB
    unsigned short* Wt      = support + (size_t)N_NODES * D;    // 0.5 MB
    int* row_start          = (int*)(Wt + (size_t)D * D);       // 200 KB
    unsigned short* Xb = (unsigned short*)d_out;                // scratch in d_out, overwritten by spmm

    cvt_kernel<<<12500, 256, 0, stream>>>(X, Xb);
    wt_kernel<<<(D * D) / 256, 256, 0, stream>>>(W, Wt);
    rowptr_kernel<<<(N_NODES + 256) / 256, 256, 0, stream>>>(rows, row_start);

    dim3 gg((N_NODES + 127) / 128, D / 128);
    gemm_kernel<<<gg, 256, 0, stream>>>(Xb, Wt, (__hip_bfloat16*)support);

    spmm_kernel<<<N_NODES, 256, 0, stream>>>(support, cols, vals, row_start, out);
}

// Round 4
// 446.100 us; speedup vs baseline: 1.0605x; 1.0542x over previous
//
#include <hip/hip_runtime.h>
#include <hip/hip_bf16.h>

#define N_NODES 50000
#define N_EDGES 1600000
#define D 512

typedef __attribute__((ext_vector_type(8))) short short8;
typedef __attribute__((ext_vector_type(4))) float f32x4;
typedef __attribute__((ext_vector_type(2))) float f32x2;
typedef __attribute__((ext_vector_type(8))) unsigned short u16x8;

__device__ __forceinline__ void async_copy16(const void* g, void* l) {
    __builtin_amdgcn_global_load_lds(
        (const __attribute__((address_space(1))) unsigned int*)g,
        (__attribute__((address_space(3))) unsigned int*)l, 16, 0, 0);
}

// --- W transpose + cast: Wt[n][k] = bf16(W[k][n]) ---
__global__ __launch_bounds__(256) void wt_kernel(const float* __restrict__ W,
                                                 unsigned short* __restrict__ Wt) {
    int idx = blockIdx.x * 256 + threadIdx.x;
    int k = idx >> 9;
    int n = idx & 511;
    Wt[n * D + k] = __bfloat16_as_ushort(__float2bfloat16(W[k * D + n]));
}

// --- CSR row_start from sorted adj_rows ---
__global__ __launch_bounds__(256) void rowptr_kernel(const int* __restrict__ rows,
                                                     int* __restrict__ row_start) {
    int r = blockIdx.x * 256 + threadIdx.x;
    if (r > N_NODES) return;
    int lo = 0, hi = N_EDGES;
    while (lo < hi) {
        int mid = (lo + hi) >> 1;
        if (rows[mid] < r) lo = mid + 1; else hi = mid;
    }
    row_start[r] = lo;
}

// --- support = bf16(bf16(X) @ Wt^T), fused fp32->bf16 in A staging ---
// v4: skinny-N streaming GEMM. BM=128 x BN=256 x BK=32, 512 thr (8 waves, 2Mx4N).
// A is reg-staged from fp32 X (global f32x4 -> cvt -> ds_write_b128): kills the
// cvt prepass AND the Xb round-trip (X read exactly once per N-sibling; B-slice
// is L2-resident, 0.5 MB). B staged via global_load_lds with the chunk map
// cid=c*512+t (wave-uniform base + lane*16B respected). Double-buffered, one
// barrier per K-iter. Conversion rounding + K order identical to v1 ->
// support bit-identical.
#define BM 128
#define BN 256
#define BK 32

__global__ __launch_bounds__(512, 4) void gemm_kernel(const float* __restrict__ X,
                                                      const unsigned short* __restrict__ Wt,
                                                      __hip_bfloat16* __restrict__ support) {
    __shared__ unsigned short As[2][BM * BK];   // 16 KB total
    __shared__ unsigned short Bs[2][BN * BK];   // 32 KB total

    const int t = threadIdx.x;
    const int lane = t & 63;
    const int w = t >> 6;
    const int wm = (w >> 2) * 64;          // 2 M-waves
    const int wn = (w & 3) * 64;           // 4 N-waves
    const int bid = blockIdx.x;
    const int m0 = (bid >> 1) * BM;        // n-fast: siblings share A panel in L2
    const int n0 = (bid & 1) * BN;
    const int l15 = lane & 15;
    const int quad = lane >> 4;

    f32x4 acc[4][4];
#pragma unroll
    for (int i = 0; i < 4; ++i)
#pragma unroll
        for (int j = 0; j < 4; ++j) acc[i][j] = (f32x4)(0.0f);

    // A staging: thread t loads 8 f32 of row (t>>2), cols (t&3)*8 .. +8
    int arow = m0 + (t >> 2);
    if (arow > N_NODES - 1) arow = N_NODES - 1;
    const float* abase = X + (size_t)arow * D + (t & 3) * 8;
    const int awr = (t >> 2) * BK + (t & 3) * 8;   // LDS offset (shorts), 16B-aligned

    // B staging: chunk cid = c*512 + t; n = cid>>2, kc = cid&3
    // dest = Bs + cid*8 shorts (lane-linear within each wave-instr), src per-lane.

    // ---- prologue: stage K-tile 0 into buffer 0 ----
    {
        f32x4 a0 = *(const f32x4*)abase;
        f32x4 a1 = *(const f32x4*)(abase + 4);
#pragma unroll
        for (int c = 0; c < 2; ++c) {
            int cid = c * 512 + t;
            async_copy16(Wt + (size_t)(n0 + (cid >> 2)) * D + (cid & 3) * 8,
                         &Bs[0][cid * 8]);
        }
        u16x8 u;
#pragma unroll
        for (int k = 0; k < 4; ++k) {
            u[k]     = __bfloat16_as_ushort(__float2bfloat16(a0[k]));
            u[k + 4] = __bfloat16_as_ushort(__float2bfloat16(a1[k]));
        }
        *(u16x8*)(&As[0][awr]) = u;
    }
    __syncthreads();

    int cur = 0;
    for (int kt = 0; kt < D / BK; ++kt) {
        f32x4 a0n, a1n;
        const int nxt = cur ^ 1;
        if (kt < D / BK - 1) {
            const int k0n = (kt + 1) * BK;
            // A loads first (so their waitcnt leaves B asyncs in flight)
            a0n = *(const f32x4*)(abase + k0n);
            a1n = *(const f32x4*)(abase + k0n + 4);
#pragma unroll
            for (int c = 0; c < 2; ++c) {
                int cid = c * 512 + t;
                async_copy16(Wt + (size_t)(n0 + (cid >> 2)) * D + k0n + (cid & 3) * 8,
                             &Bs[nxt][cid * 8]);
            }
        }

        short8 af[4], bf[4];
#pragma unroll
        for (int i = 0; i < 4; ++i) af[i] = *(const short8*)(&As[cur][(wm + i * 16 + l15) * BK + quad * 8]);
#pragma unroll
        for (int j = 0; j < 4; ++j) bf[j] = *(const short8*)(&Bs[cur][(wn + j * 16 + l15) * BK + quad * 8]);
#pragma unroll
        for (int i = 0; i < 4; ++i)
#pragma unroll
            for (int j = 0; j < 4; ++j)
                acc[i][j] = __builtin_amdgcn_mfma_f32_16x16x32_bf16(af[i], bf[j], acc[i][j], 0, 0, 0);

        if (kt < D / BK - 1) {
            u16x8 u;
#pragma unroll
            for (int k = 0; k < 4; ++k) {
                u[k]     = __bfloat16_as_ushort(__float2bfloat16(a0n[k]));
                u[k + 4] = __bfloat16_as_ushort(__float2bfloat16(a1n[k]));
            }
            *(u16x8*)(&As[nxt][awr]) = u;
        }
        __syncthreads();
        cur ^= 1;
    }

#pragma unroll
    for (int i = 0; i < 4; ++i) {
        int grow = m0 + wm + i * 16 + quad * 4;
#pragma unroll
        for (int j = 0; j < 4; ++j) {
            int gc = n0 + wn + j * 16 + l15;
#pragma unroll
            for (int rr = 0; rr < 4; ++rr) {
                int gr = grow + rr;
                if (gr < N_NODES)
                    support[(size_t)gr * D + gc] = __float2bfloat16(acc[i][j][rr]);
            }
        }
    }
}

// --- SpMM: block per row (r0 proven layout), 8-edge unroll, nt-stores — UNCHANGED ---
__global__ __launch_bounds__(256) void spmm_kernel(const unsigned short* __restrict__ support,
                                                   const int* __restrict__ cols,
                                                   const float* __restrict__ vals,
                                                   const int* __restrict__ row_start,
                                                   float* __restrict__ out) {
    const int r = blockIdx.x;
    const int t = threadIdx.x;           // thread owns cols 2t, 2t+1
    const int s = row_start[r];
    const int e = row_start[r + 1];
    const size_t co = 2 * t;

    float ax = 0.f, ay = 0.f;
    int i = s;
    for (; i + 8 <= e; i += 8) {
        int c[8]; float v[8]; unsigned int h[8];
#pragma unroll
        for (int k = 0; k < 8; ++k) { c[k] = cols[i + k]; v[k] = vals[i + k]; }
#pragma unroll
        for (int k = 0; k < 8; ++k)
            h[k] = *(const unsigned int*)(support + (size_t)c[k] * D + co);
#pragma unroll
        for (int k = 0; k < 8; ++k) {
            ax += v[k] * __uint_as_float(h[k] << 16);          // lo bf16
            ay += v[k] * __uint_as_float(h[k] & 0xffff0000u);  // hi bf16
        }
    }
    for (; i < e; ++i) {
        int c = cols[i];
        float v = vals[i];
        unsigned int h = *(const unsigned int*)(support + (size_t)c * D + co);
        ax += v * __uint_as_float(h << 16);
        ay += v * __uint_as_float(h & 0xffff0000u);
    }
    f32x2 o; o[0] = ax; o[1] = ay;
    // nontemporal: out is streamed once; keep it out of L2 so gathers keep their lines
    __builtin_nontemporal_store(o, (f32x2*)(out + (size_t)r * D + co));
}

extern "C" void kernel_launch(void* const* d_in, const int* in_sizes, int n_in,
                              void* d_out, int out_size, void* d_ws, size_t ws_size,
                              hipStream_t stream) {
    (void)in_sizes; (void)n_in; (void)out_size; (void)ws_size;
    const float* X    = (const float*)d_in[0];
    const float* W    = (const float*)d_in[1];
    const int* rows   = (const int*)d_in[2];
    const int* cols   = (const int*)d_in[3];
    const float* vals = (const float*)d_in[4];
    float* out = (float*)d_out;

    unsigned short* support = (unsigned short*)d_ws;            // 51.2 MB
    unsigned short* Wt      = support + (size_t)N_NODES * D;    // 0.5 MB
    int* row_start          = (int*)(Wt + (size_t)D * D);       // 200 KB

    wt_kernel<<<(D * D) / 256, 256, 0, stream>>>(W, Wt);
    rowptr_kernel<<<(N_NODES + 256) / 256, 256, 0, stream>>>(rows, row_start);

    const int mblocks = (N_NODES + BM - 1) / BM;   // 391
    gemm_kernel<<<mblocks * 2, 512, 0, stream>>>(X, Wt, (__hip_bfloat16*)support);

    spmm_kernel<<<N_NODES, 256, 0, stream>>>(support, cols, vals, row_start, out);
}